// Round 8
// baseline (173.774 us; speedup 1.0000x reference)
//
#include <hip/hip_runtime.h>

typedef __bf16 bf16_t;
typedef __bf16 bf16x4 __attribute__((ext_vector_type(4)));
typedef __bf16 bf16x8 __attribute__((ext_vector_type(8)));
typedef float  f32x4  __attribute__((ext_vector_type(4)));

typedef const __attribute__((address_space(1))) void gvoid_t;
typedef __attribute__((address_space(3))) void lvoid_t;

#define N_NODES 8192
#define FEAT    1024
#define NCLS    64
#define TK      32

// ---- wave-wide min reductions via DPP (result broadcast via readlane 63) ----
__device__ __forceinline__ float wave_min_f32(float v) {
  int x = __float_as_int(v), t;
#define STEPF(ctrl) t = __builtin_amdgcn_update_dpp(x, x, ctrl, 0xf, 0xf, false); \
                    v = fminf(v, __int_as_float(t)); x = __float_as_int(v);
  STEPF(0x111)  // row_shr:1
  STEPF(0x112)  // row_shr:2
  STEPF(0x114)  // row_shr:4
  STEPF(0x118)  // row_shr:8
  STEPF(0x142)  // row_bcast:15
  STEPF(0x143)  // row_bcast:31
#undef STEPF
  return __int_as_float(__builtin_amdgcn_readlane(x, 63));
}

__device__ __forceinline__ unsigned wave_min_u32(unsigned v) {
  int x = (int)v, t;
#define STEPU(ctrl) t = __builtin_amdgcn_update_dpp(x, x, ctrl, 0xf, 0xf, false); \
                    x = (int)((unsigned)x < (unsigned)t ? (unsigned)x : (unsigned)t);
  STEPU(0x111)
  STEPU(0x112)
  STEPU(0x114)
  STEPU(0x118)
  STEPU(0x142)
  STEPU(0x143)
#undef STEPU
  return (unsigned)__builtin_amdgcn_readlane(x, 63);
}

// ---------------- merged transpose+convert for W1 and W2 ----------------
__global__ __launch_bounds__(256) void transpose_cvt_kernel(const float* __restrict__ W1,
                                                            bf16_t* __restrict__ W1t,
                                                            const float* __restrict__ W2,
                                                            bf16_t* __restrict__ W2t) {
  __shared__ float tile[64][65];
  const float* in;
  bf16_t* out;
  int cols, bx;
  if (blockIdx.x < 16) { in = W1; out = W1t; cols = FEAT; bx = blockIdx.x; }
  else                 { in = W2; out = W2t; cols = NCLS; bx = 0; }
  const int by = blockIdx.y;
  const int tid = threadIdx.x;
#pragma unroll
  for (int i = 0; i < 16; ++i) {
    int li = i * 256 + tid;
    int r = li >> 6, c = li & 63;
    tile[r][c] = in[(size_t)(by * 64 + r) * cols + bx * 64 + c];
  }
  __syncthreads();
#pragma unroll
  for (int i = 0; i < 16; ++i) {
    int li = i * 256 + tid;
    int r = li >> 6, c = li & 63;
    out[(size_t)(bx * 64 + r) * FEAT + by * 64 + c] = (__bf16)tile[c][r];
  }
}

// ---- fused: blocks 0..511 = gemm1 (xW1 = x @ W1t^T, bf16 out);
//      blocks 512..8703 = exact top-K per adj row + edge weights.
// gemm blocks dispatch first -> co-resident with HBM-bound topk blocks;
// MFMA work hides under the 256MB adj scan (separate pipes, m114).
#define GEMM_BLOCKS 512
__global__ __launch_bounds__(256, 2) void fused_kernel(const float* __restrict__ adj,
                                                       const float* __restrict__ alphap,
                                                       const float* __restrict__ x,
                                                       const bf16_t* __restrict__ W1t,
                                                       bf16_t* __restrict__ xW1,
                                                       int* __restrict__ idx_out,
                                                       float* __restrict__ w_out) {
  constexpr int BM = 128, BN = 128;
  constexpr int LDSA = BM * 64;   // 8 KB: BM rows x 32 k x 2B (bf16)
  constexpr int LDSB = BN * 64;   // 8 KB
  __shared__ char lds[2][LDSA + LDSB];   // 32 KB (shared by both branches)
  const int tid = threadIdx.x;

  if (blockIdx.x < GEMM_BLOCKS) {
    // ================= gemm1 branch =================
    const int j = blockIdx.x;
    const int bm0 = (j >> 3) * BM;       // 64 M-tiles
    const int bn0 = (j & 7) * BN;        // 8 N-tiles (inner -> per-XCD B slice)
    const int wid = tid >> 6, lane = tid & 63;
    const int wr = wid >> 1, wc = wid & 1;
    constexpr int WM = BM / 2, WN = BN / 2;
    constexpr int NMI = WM / 16, NNI = WN / 16;

    auto stageA = [&](int buf, int t) {   // f32 x -> cvt -> swizzled bf16 LDS
      const int k0 = t * 32;
#pragma unroll
      for (int it = 0; it < 2; ++it) {
        const int i = it * 256 + tid;     // 512 items: 128 rows x 4 k-groups
        const int r = i >> 2, g = i & 3;
        const float* src = x + (size_t)(bm0 + r) * FEAT + k0 + g * 8;
        const float4 f0 = ((const float4*)src)[0];
        const float4 f1 = ((const float4*)src)[1];
        bf16x8 o;
        o[0] = (__bf16)f0.x; o[1] = (__bf16)f0.y; o[2] = (__bf16)f0.z; o[3] = (__bf16)f0.w;
        o[4] = (__bf16)f1.x; o[5] = (__bf16)f1.y; o[6] = (__bf16)f1.z; o[7] = (__bf16)f1.w;
        *(bf16x8*)(&lds[buf][r * 64 + ((g ^ (r & 3)) * 16)]) = o;  // slot=g^(r&3)
      }
    };
    auto stageB = [&](int buf, int t) {
      const int k0 = t * 32;
#pragma unroll
      for (int li = 0; li < BN / 64; ++li) {
        const int rb = wid * (BN / 4) + li * 16;
        const int r = rb + (lane >> 2);
        const int sdat = (lane & 3) ^ (r & 3);
        const bf16_t* g = W1t + (size_t)(bn0 + r) * FEAT + k0 + sdat * 8;
        __builtin_amdgcn_global_load_lds((gvoid_t*)g, (lvoid_t*)&lds[buf][LDSA + rb * 64], 16, 0, 0);
      }
    };

    f32x4 acc[NMI][NNI];
#pragma unroll
    for (int mi = 0; mi < NMI; ++mi)
#pragma unroll
      for (int ni = 0; ni < NNI; ++ni) acc[mi][ni] = (f32x4){0.f, 0.f, 0.f, 0.f};

    const int nT = FEAT / 32;
    stageB(0, 0);
    stageA(0, 0);
    __syncthreads();
    for (int t = 0; t < nT; ++t) {
      const int cur = t & 1;
      if (t + 1 < nT) { stageB(cur ^ 1, t + 1); stageA(cur ^ 1, t + 1); }
      const char* la = &lds[cur][0];
      const char* lb = &lds[cur][LDSA];
      const int s = lane >> 4;
      bf16x8 af[NMI], bfr[NNI];
#pragma unroll
      for (int mi = 0; mi < NMI; ++mi) {
        const int m = wr * WM + mi * 16 + (lane & 15);
        af[mi] = *(const bf16x8*)(la + m * 64 + ((s ^ (m & 3)) * 16));
      }
#pragma unroll
      for (int ni = 0; ni < NNI; ++ni) {
        const int n = wc * WN + ni * 16 + (lane & 15);
        bfr[ni] = *(const bf16x8*)(lb + n * 64 + ((s ^ (n & 3)) * 16));
      }
#pragma unroll
      for (int mi = 0; mi < NMI; ++mi)
#pragma unroll
        for (int ni = 0; ni < NNI; ++ni)
          acc[mi][ni] = __builtin_amdgcn_mfma_f32_16x16x32_bf16(af[mi], bfr[ni], acc[mi][ni], 0, 0, 0);
      __syncthreads();
    }

#pragma unroll
    for (int mi = 0; mi < NMI; ++mi)
#pragma unroll
      for (int ni = 0; ni < NNI; ++ni)
#pragma unroll
        for (int j4 = 0; j4 < 4; ++j4) {
          const int r = bm0 + wr * WM + mi * 16 + (lane >> 4) * 4 + j4;
          const int c = bn0 + wc * WN + ni * 16 + (lane & 15);
          xW1[(size_t)r * FEAT + c] = (__bf16)acc[mi][ni][j4];
        }
    return;
  }

  // ================= topk branch =================
  float* svals = (float*)&lds[0][0];
  int*   sidx  = (int*)&lds[0][1024];
  int*   scnt  = (int*)&lds[0][2048];
  const int row = blockIdx.x - GEMM_BLOCKS;
  const float* arow = adj + (size_t)row * N_NODES;
  float thr = 1.0f / 128.0f;  // E[count]=64 for uniform[0,1)
  int cnt = 0;
  for (int attempt = 0; attempt < 24; ++attempt) {
    __syncthreads();
    if (tid == 0) *scnt = 0;
    __syncthreads();
#pragma unroll
    for (int v = 0; v < 8; ++v) {
      int vi = v * 256 + tid;
      float4 q = ((const float4*)arow)[vi];
      int base = vi * 4;
      if (q.x < thr) { int p = atomicAdd(scnt, 1); if (p < 256) { svals[p] = q.x; sidx[p] = base;     } }
      if (q.y < thr) { int p = atomicAdd(scnt, 1); if (p < 256) { svals[p] = q.y; sidx[p] = base + 1; } }
      if (q.z < thr) { int p = atomicAdd(scnt, 1); if (p < 256) { svals[p] = q.z; sidx[p] = base + 2; } }
      if (q.w < thr) { int p = atomicAdd(scnt, 1); if (p < 256) { svals[p] = q.w; sidx[p] = base + 3; } }
    }
    __syncthreads();
    cnt = *scnt;
    if (cnt >= TK && cnt <= 256) break;  // exact: all K smallest are < thr
    thr = (cnt < TK) ? thr * 2.0f : thr * 0.5f;
  }
  const int M = cnt < 256 ? cnt : 256;

  if (tid < 64) {
    const int lane = tid;
    const float INF = __int_as_float(0x7f800000);
    float cv[4];
    int   ci[4];
#pragma unroll
    for (int j = 0; j < 4; ++j) {
      int slot = lane + j * 64;
      if (slot < M) { cv[j] = svals[slot]; ci[j] = sidx[slot]; }
      else          { cv[j] = INF;         ci[j] = 0x7fffffff; }
    }
    float selv = 0.f;
    int   seli = 0;
    for (int k = 0; k < TK; ++k) {
      const float lv = fminf(fminf(cv[0], cv[1]), fminf(cv[2], cv[3]));
      const float wv = wave_min_f32(lv);
      unsigned li = 0xffffffffu;
#pragma unroll
      for (int j = 0; j < 4; ++j)
        if (cv[j] == wv) li = li < (unsigned)ci[j] ? li : (unsigned)ci[j];
      const unsigned wi = wave_min_u32(li);
      if (lane == k) { selv = wv; seli = (int)wi; }
#pragma unroll
      for (int j = 0; j < 4; ++j)
        if (cv[j] == wv && (unsigned)ci[j] == wi) cv[j] = INF;
    }
    const float a = alphap[0];
    const float e = (lane < TK) ? expf(-a * selv) : 0.0f;
    float ssum = e;
#pragma unroll
    for (int off = 1; off < 64; off <<= 1) ssum += __shfl_xor(ssum, off);
    if (lane < TK) {
      idx_out[(size_t)row * TK + lane] = seli & (N_NODES - 1);
      w_out[(size_t)row * TK + lane]   = e / ssum;
    }
  }
}

// ------- fused spmm1+bias+relu+gemm2, 8-way feature-split for L2 locality -------
#define SROWS  16
#define SCHUNK 128
#define NCHUNK 8
__global__ __launch_bounds__(256) void spmm_gemm2_kernel(const bf16_t* __restrict__ xW1,
                                                         const int* __restrict__ idxm,
                                                         const float* __restrict__ wm,
                                                         const float* __restrict__ b1,
                                                         const bf16_t* __restrict__ W2t,
                                                         float* __restrict__ part) {
  const int tid = threadIdx.x;
  const int c  = blockIdx.x & (NCHUNK - 1);
  const int rg = blockIdx.x >> 3;
  const int r0 = rg * SROWS;
  const int f0 = c * SCHUNK;
  __shared__ int    snb[SROWS][TK];
  __shared__ float  swt[SROWS][TK];
  __shared__ bf16_t hls[SROWS][SCHUNK];  // XOR-swizzled groups of 8
  ((int2*)&snb[0][0])[tid]   = ((const int2*)(idxm + (size_t)r0 * TK))[tid];
  ((float2*)&swt[0][0])[tid] = ((const float2*)(wm + (size_t)r0 * TK))[tid];
  __syncthreads();
  const int wid = tid >> 6, lane = tid & 63;
  const int gr = tid >> 4;            // gather row 0..15
  const int gc = (tid & 15) * 8;      // feat base within chunk (8 feats/thread)

  float a[8];
#pragma unroll
  for (int j = 0; j < 8; ++j) a[j] = 0.f;
#pragma unroll 8
  for (int k = 0; k < TK; ++k) {
    const bf16x8 v = *(const bf16x8*)(xW1 + (size_t)snb[gr][k] * FEAT + f0 + gc);
    const float wk = swt[gr][k];
#pragma unroll
    for (int j = 0; j < 8; ++j) a[j] += wk * (float)v[j];
  }
  const float4 b0 = ((const float4*)(b1 + f0 + gc))[0];
  const float4 b1v = ((const float4*)(b1 + f0 + gc))[1];
  bf16x8 o0;
  o0[0] = (__bf16)fmaxf(a[0] + b0.x, 0.f);
  o0[1] = (__bf16)fmaxf(a[1] + b0.y, 0.f);
  o0[2] = (__bf16)fmaxf(a[2] + b0.z, 0.f);
  o0[3] = (__bf16)fmaxf(a[3] + b0.w, 0.f);
  o0[4] = (__bf16)fmaxf(a[4] + b1v.x, 0.f);
  o0[5] = (__bf16)fmaxf(a[5] + b1v.y, 0.f);
  o0[6] = (__bf16)fmaxf(a[6] + b1v.z, 0.f);
  o0[7] = (__bf16)fmaxf(a[7] + b1v.w, 0.f);
  const int g0 = (gc >> 3);           // group 0..15
  char* hb = (char*)&hls[0][0];
  *(bf16x8*)(hb + gr * (SCHUNK * 2) + ((g0 ^ (gr & 7)) * 16)) = o0;

  // prefetch W2t B-frags before the barrier (independent of LDS writes)
  const int s = lane >> 4;
  const int m = lane & 15;
  const int n = wid * 16 + (lane & 15);
  bf16x8 bfr[SCHUNK / 32];
#pragma unroll
  for (int ks = 0; ks < SCHUNK / 32; ++ks)
    bfr[ks] = *(const bf16x8*)(W2t + (size_t)n * FEAT + f0 + ks * 32 + s * 8);
  __syncthreads();

  // MFMA: out[16 x 64] K-partial (K=SCHUNK); this wave owns cols wid*16..
  f32x4 acc = (f32x4){0.f, 0.f, 0.f, 0.f};
  const char* hr = (char*)&hls[0][0] + m * (SCHUNK * 2);
#pragma unroll
  for (int ks = 0; ks < SCHUNK / 32; ++ks) {
    const int g = ks * 4 + s;
    const bf16x8 afrag = *(const bf16x8*)(hr + ((g ^ (m & 7)) * 16));
    acc = __builtin_amdgcn_mfma_f32_16x16x32_bf16(afrag, bfr[ks], acc, 0, 0, 0);
  }
#pragma unroll
  for (int j = 0; j < 4; ++j) {
    const int r = r0 + (lane >> 4) * 4 + j;
    const int col = wid * 16 + (lane & 15);
    part[((size_t)c * N_NODES + r) * NCLS + col] = acc[j];
  }
}

// ---------------- out2 = sum of 8 partials (fixed order, deterministic) ----
__global__ __launch_bounds__(256) void reduce8_kernel(const float* __restrict__ part,
                                                      float* __restrict__ out2) {
  const int i = blockIdx.x * 256 + threadIdx.x;   // over N*NCLS/4 float4s
  float4 s = ((const float4*)(part))[i];
#pragma unroll
  for (int c = 1; c < NCHUNK; ++c) {
    const float4 p = ((const float4*)(part + (size_t)c * N_NODES * NCLS))[i];
    s.x += p.x; s.y += p.y; s.z += p.z; s.w += p.w;
  }
  ((float4*)out2)[i] = s;
}

// ---------------- spmm2 + b2 + log_softmax: one wave per output row ----------------
__global__ __launch_bounds__(256) void final_kernel(const float* __restrict__ out2,
                                                    const int* __restrict__ idxm,
                                                    const float* __restrict__ wm,
                                                    const float* __restrict__ b2,
                                                    float* __restrict__ out) {
  const int wid = threadIdx.x >> 6, lane = threadIdx.x & 63;
  const int row = blockIdx.x * 4 + wid;
  const int kk = lane & 31;
  const float wv = wm[(size_t)row * TK + kk];
  const int   iv = idxm[(size_t)row * TK + kk];
  float acc = 0.f;
#pragma unroll 8
  for (int k = 0; k < TK; ++k) {
    const float wk = __shfl(wv, k);
    const int   ik = __shfl(iv, k);
    acc += wk * out2[(size_t)ik * NCLS + lane];
  }
  const float logit = acc + b2[lane];
  float m = logit;
#pragma unroll
  for (int off = 1; off < 64; off <<= 1) m = fmaxf(m, __shfl_xor(m, off));
  const float e = expf(logit - m);
  float ssum = e;
#pragma unroll
  for (int off = 1; off < 64; off <<= 1) ssum += __shfl_xor(ssum, off);
  out[(size_t)row * NCLS + lane] = (logit - m) - logf(ssum);
}

extern "C" void kernel_launch(void* const* d_in, const int* in_sizes, int n_in,
                              void* d_out, int out_size, void* d_ws, size_t ws_size,
                              hipStream_t stream) {
  (void)in_sizes; (void)n_in; (void)out_size; (void)ws_size;
  const float* x     = (const float*)d_in[0];
  const float* adj   = (const float*)d_in[1];
  const float* W1    = (const float*)d_in[2];
  const float* b1    = (const float*)d_in[3];
  const float* W2    = (const float*)d_in[4];
  const float* b2    = (const float*)d_in[5];
  const float* alpha = (const float*)d_in[6];

  char* ws = (char*)d_ws;
  const size_t MB = 1024 * 1024;
  bf16_t* xW1  = (bf16_t*)(ws + 16 * MB);   // 16 MB
  bf16_t* W1t  = (bf16_t*)(ws + 48 * MB);   // 2 MB
  bf16_t* W2t  = (bf16_t*)(ws + 50 * MB);   // 128KB
  float*  out2 = (float*)(ws + 51 * MB);    // 2 MB
  int*    idxm = (int*)(ws + 53 * MB);      // 1 MB
  float*  wm   = (float*)(ws + 54 * MB);    // 1 MB
  float*  part = (float*)(ws + 56 * MB);    // 16 MB: 8 x [8192][64] f32 K-partials

  transpose_cvt_kernel<<<dim3(17, 16), dim3(256), 0, stream>>>(W1, W1t, W2, W2t);
  fused_kernel<<<dim3(GEMM_BLOCKS + N_NODES), dim3(256), 0, stream>>>(
      adj, alpha, x, W1t, xW1, idxm, wm);
  spmm_gemm2_kernel<<<dim3((N_NODES / SROWS) * NCHUNK), dim3(256), 0, stream>>>(
      xW1, idxm, wm, b1, W2t, part);
  reduce8_kernel<<<dim3(N_NODES * NCLS / 4 / 256), dim3(256), 0, stream>>>(part, out2);
  final_kernel<<<dim3(N_NODES / 4), dim3(256), 0, stream>>>(out2, idxm, wm, b2, (float*)d_out);
}

// Round 9
// 140.210 us; speedup vs baseline: 1.2394x; 1.2394x over previous
//
#include <hip/hip_runtime.h>

typedef __bf16 bf16_t;
typedef __bf16 bf16x4 __attribute__((ext_vector_type(4)));
typedef __bf16 bf16x8 __attribute__((ext_vector_type(8)));
typedef float  f32x4  __attribute__((ext_vector_type(4)));

typedef const __attribute__((address_space(1))) void gvoid_t;
typedef __attribute__((address_space(3))) void lvoid_t;

#define N_NODES 8192
#define FEAT    1024
#define NCLS    64
#define TK      32

// ---- wave-wide min reductions via DPP (result broadcast via readlane 63) ----
__device__ __forceinline__ float wave_min_f32(float v) {
  int x = __float_as_int(v), t;
#define STEPF(ctrl) t = __builtin_amdgcn_update_dpp(x, x, ctrl, 0xf, 0xf, false); \
                    v = fminf(v, __int_as_float(t)); x = __float_as_int(v);
  STEPF(0x111)  // row_shr:1
  STEPF(0x112)  // row_shr:2
  STEPF(0x114)  // row_shr:4
  STEPF(0x118)  // row_shr:8
  STEPF(0x142)  // row_bcast:15
  STEPF(0x143)  // row_bcast:31
#undef STEPF
  return __int_as_float(__builtin_amdgcn_readlane(x, 63));
}

__device__ __forceinline__ unsigned wave_min_u32(unsigned v) {
  int x = (int)v, t;
#define STEPU(ctrl) t = __builtin_amdgcn_update_dpp(x, x, ctrl, 0xf, 0xf, false); \
                    x = (int)((unsigned)x < (unsigned)t ? (unsigned)x : (unsigned)t);
  STEPU(0x111)
  STEPU(0x112)
  STEPU(0x114)
  STEPU(0x118)
  STEPU(0x142)
  STEPU(0x143)
#undef STEPU
  return (unsigned)__builtin_amdgcn_readlane(x, 63);
}

// ------- topk (blocks < N_NODES) + merged W1/W2 transpose (blocks >= N_NODES) -------
__global__ __launch_bounds__(256) void topk_kernel(const float* __restrict__ adj,
                                                   const float* __restrict__ alphap,
                                                   const float* __restrict__ x,
                                                   bf16_t* __restrict__ x_bf,
                                                   int* __restrict__ idx_out,
                                                   float* __restrict__ w_out,
                                                   const float* __restrict__ W1,
                                                   bf16_t* __restrict__ W1t,
                                                   const float* __restrict__ W2,
                                                   bf16_t* __restrict__ W2t) {
  const int tid = threadIdx.x;
  __shared__ float tile[64][65];
  __shared__ float svals[256];
  __shared__ int   sidx[256];
  __shared__ int   scnt;

  if (blockIdx.x >= N_NODES) {
    // ---- transpose+convert branch ----
    const int tb = blockIdx.x - N_NODES;   // 0..271
    const int bxi = tb % 17, by = tb / 17;
    const float* in;
    bf16_t* out;
    int cols, bx;
    if (bxi < 16) { in = W1; out = W1t; cols = FEAT; bx = bxi; }
    else          { in = W2; out = W2t; cols = NCLS; bx = 0; }
#pragma unroll
    for (int i = 0; i < 16; ++i) {
      int li = i * 256 + tid;
      int r = li >> 6, c = li & 63;
      tile[r][c] = in[(size_t)(by * 64 + r) * cols + bx * 64 + c];
    }
    __syncthreads();
#pragma unroll
    for (int i = 0; i < 16; ++i) {
      int li = i * 256 + tid;
      int r = li >> 6, c = li & 63;
      out[(size_t)(bx * 64 + r) * FEAT + by * 64 + c] = (__bf16)tile[c][r];
    }
    return;
  }

  const int row = blockIdx.x;
  {
    const float4 v = ((const float4*)(x + (size_t)row * FEAT))[tid];
    bf16x4 o;
    o[0] = (__bf16)v.x; o[1] = (__bf16)v.y; o[2] = (__bf16)v.z; o[3] = (__bf16)v.w;
    ((bf16x4*)(x_bf + (size_t)row * FEAT))[tid] = o;
  }

  const float* arow = adj + (size_t)row * N_NODES;
  float thr = 1.0f / 128.0f;  // E[count]=64 for uniform[0,1)
  int cnt = 0;
  for (int attempt = 0; attempt < 24; ++attempt) {
    __syncthreads();
    if (tid == 0) scnt = 0;
    __syncthreads();
#pragma unroll
    for (int v = 0; v < 8; ++v) {
      int vi = v * 256 + tid;
      float4 q = ((const float4*)arow)[vi];
      int base = vi * 4;
      if (q.x < thr) { int p = atomicAdd(&scnt, 1); if (p < 256) { svals[p] = q.x; sidx[p] = base;     } }
      if (q.y < thr) { int p = atomicAdd(&scnt, 1); if (p < 256) { svals[p] = q.y; sidx[p] = base + 1; } }
      if (q.z < thr) { int p = atomicAdd(&scnt, 1); if (p < 256) { svals[p] = q.z; sidx[p] = base + 2; } }
      if (q.w < thr) { int p = atomicAdd(&scnt, 1); if (p < 256) { svals[p] = q.w; sidx[p] = base + 3; } }
    }
    __syncthreads();
    cnt = scnt;
    if (cnt >= TK && cnt <= 256) break;  // exact: all K smallest are < thr
    thr = (cnt < TK) ? thr * 2.0f : thr * 0.5f;
  }
  const int M = cnt < 256 ? cnt : 256;

  if (tid < 64) {
    const int lane = tid;
    const float INF = __int_as_float(0x7f800000);
    float cv[4];
    int   ci[4];
#pragma unroll
    for (int j = 0; j < 4; ++j) {
      int slot = lane + j * 64;
      if (slot < M) { cv[j] = svals[slot]; ci[j] = sidx[slot]; }
      else          { cv[j] = INF;         ci[j] = 0x7fffffff; }
    }
    float selv = 0.f;
    int   seli = 0;
    for (int k = 0; k < TK; ++k) {
      const float lv = fminf(fminf(cv[0], cv[1]), fminf(cv[2], cv[3]));
      const float wv = wave_min_f32(lv);
      unsigned li = 0xffffffffu;
#pragma unroll
      for (int j = 0; j < 4; ++j)
        if (cv[j] == wv) li = li < (unsigned)ci[j] ? li : (unsigned)ci[j];
      const unsigned wi = wave_min_u32(li);
      if (lane == k) { selv = wv; seli = (int)wi; }
#pragma unroll
      for (int j = 0; j < 4; ++j)
        if (cv[j] == wv && (unsigned)ci[j] == wi) cv[j] = INF;
    }
    const float a = alphap[0];
    const float e = (lane < TK) ? expf(-a * selv) : 0.0f;
    float ssum = e;
#pragma unroll
    for (int off = 1; off < 64; off <<= 1) ssum += __shfl_xor(ssum, off);
    if (lane < TK) {
      idx_out[(size_t)row * TK + lane] = seli & (N_NODES - 1);
      w_out[(size_t)row * TK + lane]   = e / ssum;
    }
  }
}

// ---------------- bf16 MFMA GEMM: C[M,N] = A[M,K] * Bt[N,K]^T ----------------
// BM=64/BN=256: A re-read = 4 passes (64MB from L3) vs 8 at 128x128;
// B panel 512KB stays L2-resident per XCD. Same MFMA count & accumulation order.
template <int BM, int BN, bool OUT_BF16>
__global__ __launch_bounds__(256, 2) void gemm_bt_kernel(const bf16_t* __restrict__ A,
                                                         const bf16_t* __restrict__ Bt,
                                                         void* __restrict__ Cp,
                                                         int M, int N, int Kd) {
  constexpr int LDSA = BM * 64;   // BM rows x 32 k x 2B
  constexpr int LDSB = BN * 64;
  __shared__ char lds[2][LDSA + LDSB];
  const int tid = threadIdx.x;
  const int wid = tid >> 6, lane = tid & 63;
  const int bm0 = blockIdx.x * BM, bn0 = blockIdx.y * BN;
  const int wr = wid >> 1, wc = wid & 1;
  constexpr int WM = BM / 2, WN = BN / 2;
  constexpr int NMI = WM / 16, NNI = WN / 16;

  auto stage = [&](int buf, int t) {
    const int k0 = t * 32;
#pragma unroll
    for (int li = 0; li < BM / 64; ++li) {
      const int rb = wid * (BM / 4) + li * 16;
      const int r = rb + (lane >> 2);
      const int sdat = (lane & 3) ^ (r & 3);
      const bf16_t* g = A + (size_t)(bm0 + r) * Kd + k0 + sdat * 8;
      __builtin_amdgcn_global_load_lds((gvoid_t*)g, (lvoid_t*)&lds[buf][rb * 64], 16, 0, 0);
    }
#pragma unroll
    for (int li = 0; li < BN / 64; ++li) {
      const int rb = wid * (BN / 4) + li * 16;
      const int r = rb + (lane >> 2);
      const int sdat = (lane & 3) ^ (r & 3);
      const bf16_t* g = Bt + (size_t)(bn0 + r) * Kd + k0 + sdat * 8;
      __builtin_amdgcn_global_load_lds((gvoid_t*)g, (lvoid_t*)&lds[buf][LDSA + rb * 64], 16, 0, 0);
    }
  };

  f32x4 acc[NMI][NNI];
#pragma unroll
  for (int mi = 0; mi < NMI; ++mi)
#pragma unroll
    for (int ni = 0; ni < NNI; ++ni) acc[mi][ni] = (f32x4){0.f, 0.f, 0.f, 0.f};

  const int nT = Kd / 32;
  stage(0, 0);
  __syncthreads();
  for (int t = 0; t < nT; ++t) {
    const int cur = t & 1;
    if (t + 1 < nT) stage(cur ^ 1, t + 1);
    const char* la = &lds[cur][0];
    const char* lb = &lds[cur][LDSA];
    const int s = lane >> 4;
    bf16x8 af[NMI], bfr[NNI];
#pragma unroll
    for (int mi = 0; mi < NMI; ++mi) {
      const int m = wr * WM + mi * 16 + (lane & 15);
      af[mi] = *(const bf16x8*)(la + m * 64 + ((s ^ (m & 3)) * 16));
    }
#pragma unroll
    for (int ni = 0; ni < NNI; ++ni) {
      const int n = wc * WN + ni * 16 + (lane & 15);
      bfr[ni] = *(const bf16x8*)(lb + n * 64 + ((s ^ (n & 3)) * 16));
    }
#pragma unroll
    for (int mi = 0; mi < NMI; ++mi)
#pragma unroll
      for (int ni = 0; ni < NNI; ++ni)
        acc[mi][ni] = __builtin_amdgcn_mfma_f32_16x16x32_bf16(af[mi], bfr[ni], acc[mi][ni], 0, 0, 0);
    __syncthreads();
  }

#pragma unroll
  for (int mi = 0; mi < NMI; ++mi)
#pragma unroll
    for (int ni = 0; ni < NNI; ++ni)
#pragma unroll
      for (int j = 0; j < 4; ++j) {
        const int r = bm0 + wr * WM + mi * 16 + (lane >> 4) * 4 + j;
        const int c = bn0 + wc * WN + ni * 16 + (lane & 15);
        if constexpr (OUT_BF16)
          ((bf16_t*)Cp)[(size_t)r * N + c] = (__bf16)acc[mi][ni][j];
        else
          ((float*)Cp)[(size_t)r * N + c] = acc[mi][ni][j];
      }
}

// ------- fused spmm1+bias+relu+gemm2, 8-way feature-split for L2 locality -------
// block = (row-group rg, chunk c); c = blockIdx&7 -> chunk c pinned to XCD c.
// SROWS=32: half the blocks of the SROWS=16 version -> half the prologue
// overhead; identical accumulation order (bitwise-same partials).
#define SROWS  32
#define SCHUNK 128
#define NCHUNK 8
__global__ __launch_bounds__(256) void spmm_gemm2_kernel(const bf16_t* __restrict__ xW1,
                                                         const int* __restrict__ idxm,
                                                         const float* __restrict__ wm,
                                                         const float* __restrict__ b1,
                                                         const bf16_t* __restrict__ W2t,
                                                         float* __restrict__ part) {
  const int tid = threadIdx.x;
  const int c  = blockIdx.x & (NCHUNK - 1);
  const int rg = blockIdx.x >> 3;
  const int r0 = rg * SROWS;
  const int f0 = c * SCHUNK;
  __shared__ int    snb[SROWS][TK];
  __shared__ float  swt[SROWS][TK];
  __shared__ bf16_t hls[SROWS][SCHUNK];  // XOR-swizzled groups of 8
  // 32*32 = 1024 idx + 1024 w, 256 threads -> int4/float4 each
  ((int4*)&snb[0][0])[tid]   = ((const int4*)(idxm + (size_t)r0 * TK))[tid];
  ((float4*)&swt[0][0])[tid] = ((const float4*)(wm + (size_t)r0 * TK))[tid];
  __syncthreads();
  const int wid = tid >> 6, lane = tid & 63;
  const int gr = tid >> 3;            // gather row 0..31
  const int gc = (tid & 7) * 16;      // feat base within chunk (16 feats/thread)

  float a[16];
#pragma unroll
  for (int j = 0; j < 16; ++j) a[j] = 0.f;
#pragma unroll 4
  for (int k = 0; k < TK; ++k) {
    const bf16_t* src = xW1 + (size_t)snb[gr][k] * FEAT + f0 + gc;
    const float wk = swt[gr][k];
    const bf16x8 v0 = ((const bf16x8*)src)[0];
    const bf16x8 v1 = ((const bf16x8*)src)[1];
#pragma unroll
    for (int j = 0; j < 8; ++j) a[j]     += wk * (float)v0[j];
#pragma unroll
    for (int j = 0; j < 8; ++j) a[8 + j] += wk * (float)v1[j];
  }
  const float4 b0  = ((const float4*)(b1 + f0 + gc))[0];
  const float4 b1v = ((const float4*)(b1 + f0 + gc))[1];
  const float4 b2v = ((const float4*)(b1 + f0 + gc))[2];
  const float4 b3  = ((const float4*)(b1 + f0 + gc))[3];
  bf16x8 o0, o1;
  o0[0] = (__bf16)fmaxf(a[0] + b0.x, 0.f);
  o0[1] = (__bf16)fmaxf(a[1] + b0.y, 0.f);
  o0[2] = (__bf16)fmaxf(a[2] + b0.z, 0.f);
  o0[3] = (__bf16)fmaxf(a[3] + b0.w, 0.f);
  o0[4] = (__bf16)fmaxf(a[4] + b1v.x, 0.f);
  o0[5] = (__bf16)fmaxf(a[5] + b1v.y, 0.f);
  o0[6] = (__bf16)fmaxf(a[6] + b1v.z, 0.f);
  o0[7] = (__bf16)fmaxf(a[7] + b1v.w, 0.f);
  o1[0] = (__bf16)fmaxf(a[8] + b2v.x, 0.f);
  o1[1] = (__bf16)fmaxf(a[9] + b2v.y, 0.f);
  o1[2] = (__bf16)fmaxf(a[10] + b2v.z, 0.f);
  o1[3] = (__bf16)fmaxf(a[11] + b2v.w, 0.f);
  o1[4] = (__bf16)fmaxf(a[12] + b3.x, 0.f);
  o1[5] = (__bf16)fmaxf(a[13] + b3.y, 0.f);
  o1[6] = (__bf16)fmaxf(a[14] + b3.z, 0.f);
  o1[7] = (__bf16)fmaxf(a[15] + b3.w, 0.f);
  const int g0 = (gc >> 3);           // even group 0..14
  char* hb = (char*)&hls[0][0];
  *(bf16x8*)(hb + gr * (SCHUNK * 2) + (((g0    ) ^ (gr & 7)) * 16)) = o0;
  *(bf16x8*)(hb + gr * (SCHUNK * 2) + (((g0 + 1) ^ (gr & 7)) * 16)) = o1;

  // prefetch W2t B-frags before the barrier (independent of LDS writes)
  const int s = lane >> 4;
  const int m = lane & 15;
  const int n = wid * 16 + (lane & 15);
  bf16x8 bfr[SCHUNK / 32];
#pragma unroll
  for (int ks = 0; ks < SCHUNK / 32; ++ks)
    bfr[ks] = *(const bf16x8*)(W2t + (size_t)n * FEAT + f0 + ks * 32 + s * 8);
  __syncthreads();

  // MFMA: out[32 x 64] K-partial (K=SCHUNK); wave owns cols wid*16..,
  // two 16-row m-tiles (B-frags reused across both).
  f32x4 acc[2];
  acc[0] = (f32x4){0.f, 0.f, 0.f, 0.f};
  acc[1] = (f32x4){0.f, 0.f, 0.f, 0.f};
#pragma unroll
  for (int mt = 0; mt < 2; ++mt) {
    const char* hr = (char*)&hls[0][0] + (mt * 16 + m) * (SCHUNK * 2);
#pragma unroll
    for (int ks = 0; ks < SCHUNK / 32; ++ks) {
      const int g = ks * 4 + s;
      const bf16x8 afrag = *(const bf16x8*)(hr + ((g ^ (m & 7)) * 16));
      acc[mt] = __builtin_amdgcn_mfma_f32_16x16x32_bf16(afrag, bfr[ks], acc[mt], 0, 0, 0);
    }
  }
#pragma unroll
  for (int mt = 0; mt < 2; ++mt)
#pragma unroll
    for (int j = 0; j < 4; ++j) {
      const int r = r0 + mt * 16 + (lane >> 4) * 4 + j;
      const int col = wid * 16 + (lane & 15);
      part[((size_t)c * N_NODES + r) * NCLS + col] = acc[mt][j];
    }
}

// ---------------- out2 = sum of 8 partials (fixed order, deterministic) ----
__global__ __launch_bounds__(256) void reduce8_kernel(const float* __restrict__ part,
                                                      float* __restrict__ out2) {
  const int i = blockIdx.x * 256 + threadIdx.x;   // over N*NCLS/4 float4s
  float4 s = ((const float4*)(part))[i];
#pragma unroll
  for (int c = 1; c < NCHUNK; ++c) {
    const float4 p = ((const float4*)(part + (size_t)c * N_NODES * NCLS))[i];
    s.x += p.x; s.y += p.y; s.z += p.z; s.w += p.w;
  }
  ((float4*)out2)[i] = s;
}

// ---------------- spmm2 + b2 + log_softmax: one wave per output row ----------------
__global__ __launch_bounds__(256) void final_kernel(const float* __restrict__ out2,
                                                    const int* __restrict__ idxm,
                                                    const float* __restrict__ wm,
                                                    const float* __restrict__ b2,
                                                    float* __restrict__ out) {
  const int wid = threadIdx.x >> 6, lane = threadIdx.x & 63;
  const int row = blockIdx.x * 4 + wid;
  const int kk = lane & 31;
  const float wv = wm[(size_t)row * TK + kk];
  const int   iv = idxm[(size_t)row * TK + kk];
  float acc = 0.f;
#pragma unroll 8
  for (int k = 0; k < TK; ++k) {
    const float wk = __shfl(wv, k);
    const int   ik = __shfl(iv, k);
    acc += wk * out2[(size_t)ik * NCLS + lane];
  }
  const float logit = acc + b2[lane];
  float m = logit;
#pragma unroll
  for (int off = 1; off < 64; off <<= 1) m = fmaxf(m, __shfl_xor(m, off));
  const float e = expf(logit - m);
  float ssum = e;
#pragma unroll
  for (int off = 1; off < 64; off <<= 1) ssum += __shfl_xor(ssum, off);
  out[(size_t)row * NCLS + lane] = (logit - m) - logf(ssum);
}

extern "C" void kernel_launch(void* const* d_in, const int* in_sizes, int n_in,
                              void* d_out, int out_size, void* d_ws, size_t ws_size,
                              hipStream_t stream) {
  (void)in_sizes; (void)n_in; (void)out_size; (void)ws_size;
  const float* x     = (const float*)d_in[0];
  const float* adj   = (const float*)d_in[1];
  const float* W1    = (const float*)d_in[2];
  const float* b1    = (const float*)d_in[3];
  const float* W2    = (const float*)d_in[4];
  const float* b2    = (const float*)d_in[5];
  const float* alpha = (const float*)d_in[6];

  char* ws = (char*)d_ws;
  const size_t MB = 1024 * 1024;
  bf16_t* x_bf = (bf16_t*)(ws + 0 * MB);    // 16 MB
  bf16_t* xW1  = (bf16_t*)(ws + 16 * MB);   // 16 MB
  bf16_t* W1t  = (bf16_t*)(ws + 48 * MB);   // 2 MB
  bf16_t* W2t  = (bf16_t*)(ws + 50 * MB);   // 128KB
  float*  out2 = (float*)(ws + 51 * MB);    // 2 MB
  int*    idxm = (int*)(ws + 53 * MB);      // 1 MB
  float*  wm   = (float*)(ws + 54 * MB);    // 1 MB
  float*  part = (float*)(ws + 56 * MB);    // 16 MB: 8 x [8192][64] f32 K-partials

  topk_kernel<<<dim3(N_NODES + 272), dim3(256), 0, stream>>>(
      adj, alpha, x, x_bf, idxm, wm, W1, W1t, W2, W2t);
  gemm_bt_kernel<64, 256, true><<<dim3(N_NODES / 64, FEAT / 256), dim3(256), 0, stream>>>(
      x_bf, W1t, (void*)xW1, N_NODES, FEAT, FEAT);
  spmm_gemm2_kernel<<<dim3((N_NODES / SROWS) * NCHUNK), dim3(256), 0, stream>>>(
      xW1, idxm, wm, b1, W2t, part);
  reduce8_kernel<<<dim3(N_NODES * NCLS / 4 / 256), dim3(256), 0, stream>>>(part, out2);
  final_kernel<<<dim3(N_NODES / 4), dim3(256), 0, stream>>>(out2, idxm, wm, b2, (float*)d_out);
}

// Round 10
// 135.021 us; speedup vs baseline: 1.2870x; 1.0384x over previous
//
#include <hip/hip_runtime.h>

typedef __bf16 bf16_t;
typedef __bf16 bf16x4 __attribute__((ext_vector_type(4)));
typedef __bf16 bf16x8 __attribute__((ext_vector_type(8)));
typedef float  f32x4  __attribute__((ext_vector_type(4)));

typedef const __attribute__((address_space(1))) void gvoid_t;
typedef __attribute__((address_space(3))) void lvoid_t;

#define N_NODES 8192
#define FEAT    1024
#define NCLS    64
#define TK      32

// ---- wave-wide min reductions via DPP (result broadcast via readlane 63) ----
__device__ __forceinline__ float wave_min_f32(float v) {
  int x = __float_as_int(v), t;
#define STEPF(ctrl) t = __builtin_amdgcn_update_dpp(x, x, ctrl, 0xf, 0xf, false); \
                    v = fminf(v, __int_as_float(t)); x = __float_as_int(v);
  STEPF(0x111)  // row_shr:1
  STEPF(0x112)  // row_shr:2
  STEPF(0x114)  // row_shr:4
  STEPF(0x118)  // row_shr:8
  STEPF(0x142)  // row_bcast:15
  STEPF(0x143)  // row_bcast:31
#undef STEPF
  return __int_as_float(__builtin_amdgcn_readlane(x, 63));
}

__device__ __forceinline__ unsigned wave_min_u32(unsigned v) {
  int x = (int)v, t;
#define STEPU(ctrl) t = __builtin_amdgcn_update_dpp(x, x, ctrl, 0xf, 0xf, false); \
                    x = (int)((unsigned)x < (unsigned)t ? (unsigned)x : (unsigned)t);
  STEPU(0x111)
  STEPU(0x112)
  STEPU(0x114)
  STEPU(0x118)
  STEPU(0x142)
  STEPU(0x143)
#undef STEPU
  return (unsigned)__builtin_amdgcn_readlane(x, 63);
}

// ------- topk (blocks < N_NODES) + merged W1/W2 transpose (blocks >= N_NODES) -------
__global__ __launch_bounds__(256) void topk_kernel(const float* __restrict__ adj,
                                                   const float* __restrict__ alphap,
                                                   const float* __restrict__ x,
                                                   bf16_t* __restrict__ x_bf,
                                                   int* __restrict__ idx_out,
                                                   float* __restrict__ w_out,
                                                   const float* __restrict__ W1,
                                                   bf16_t* __restrict__ W1t,
                                                   const float* __restrict__ W2,
                                                   bf16_t* __restrict__ W2t) {
  const int tid = threadIdx.x;
  __shared__ float tile[64][65];
  __shared__ float svals[256];
  __shared__ int   sidx[256];
  __shared__ int   scnt;

  if (blockIdx.x >= N_NODES) {
    // ---- transpose+convert branch ----
    const int tb = blockIdx.x - N_NODES;   // 0..271
    const int bxi = tb % 17, by = tb / 17;
    const float* in;
    bf16_t* out;
    int cols, bx;
    if (bxi < 16) { in = W1; out = W1t; cols = FEAT; bx = bxi; }
    else          { in = W2; out = W2t; cols = NCLS; bx = 0; }
#pragma unroll
    for (int i = 0; i < 16; ++i) {
      int li = i * 256 + tid;
      int r = li >> 6, c = li & 63;
      tile[r][c] = in[(size_t)(by * 64 + r) * cols + bx * 64 + c];
    }
    __syncthreads();
#pragma unroll
    for (int i = 0; i < 16; ++i) {
      int li = i * 256 + tid;
      int r = li >> 6, c = li & 63;
      out[(size_t)(bx * 64 + r) * FEAT + by * 64 + c] = (__bf16)tile[c][r];
    }
    return;
  }

  const int row = blockIdx.x;
  {
    const float4 v = ((const float4*)(x + (size_t)row * FEAT))[tid];
    bf16x4 o;
    o[0] = (__bf16)v.x; o[1] = (__bf16)v.y; o[2] = (__bf16)v.z; o[3] = (__bf16)v.w;
    ((bf16x4*)(x_bf + (size_t)row * FEAT))[tid] = o;
  }

  const float* arow = adj + (size_t)row * N_NODES;
  float thr = 1.0f / 128.0f;  // E[count]=64 for uniform[0,1)
  int cnt = 0;
  for (int attempt = 0; attempt < 24; ++attempt) {
    __syncthreads();
    if (tid == 0) scnt = 0;
    __syncthreads();
#pragma unroll
    for (int v = 0; v < 8; ++v) {
      int vi = v * 256 + tid;
      float4 q = ((const float4*)arow)[vi];
      int base = vi * 4;
      if (q.x < thr) { int p = atomicAdd(&scnt, 1); if (p < 256) { svals[p] = q.x; sidx[p] = base;     } }
      if (q.y < thr) { int p = atomicAdd(&scnt, 1); if (p < 256) { svals[p] = q.y; sidx[p] = base + 1; } }
      if (q.z < thr) { int p = atomicAdd(&scnt, 1); if (p < 256) { svals[p] = q.z; sidx[p] = base + 2; } }
      if (q.w < thr) { int p = atomicAdd(&scnt, 1); if (p < 256) { svals[p] = q.w; sidx[p] = base + 3; } }
    }
    __syncthreads();
    cnt = scnt;
    if (cnt >= TK && cnt <= 256) break;  // exact: all K smallest are < thr
    thr = (cnt < TK) ? thr * 2.0f : thr * 0.5f;
  }
  const int M = cnt < 256 ? cnt : 256;

  if (tid < 64) {
    const int lane = tid;
    const float INF = __int_as_float(0x7f800000);
    float cv[4];
    int   ci[4];
#pragma unroll
    for (int j = 0; j < 4; ++j) {
      int slot = lane + j * 64;
      if (slot < M) { cv[j] = svals[slot]; ci[j] = sidx[slot]; }
      else          { cv[j] = INF;         ci[j] = 0x7fffffff; }
    }
    float selv = 0.f;
    int   seli = 0;
    for (int k = 0; k < TK; ++k) {
      const float lv = fminf(fminf(cv[0], cv[1]), fminf(cv[2], cv[3]));
      const float wv = wave_min_f32(lv);
      unsigned li = 0xffffffffu;
#pragma unroll
      for (int j = 0; j < 4; ++j)
        if (cv[j] == wv) li = li < (unsigned)ci[j] ? li : (unsigned)ci[j];
      const unsigned wi = wave_min_u32(li);
      if (lane == k) { selv = wv; seli = (int)wi; }
#pragma unroll
      for (int j = 0; j < 4; ++j)
        if (cv[j] == wv && (unsigned)ci[j] == wi) cv[j] = INF;
    }
    const float a = alphap[0];
    const float e = (lane < TK) ? expf(-a * selv) : 0.0f;
    float ssum = e;
#pragma unroll
    for (int off = 1; off < 64; off <<= 1) ssum += __shfl_xor(ssum, off);
    if (lane < TK) {
      idx_out[(size_t)row * TK + lane] = seli & (N_NODES - 1);
      w_out[(size_t)row * TK + lane]   = e / ssum;
    }
  }
}

// ---------------- bf16 MFMA GEMM: C = A * Bt^T, 128x128 tile ----------------
// 1D grid, XCD-band mapping: XCD c (= b%8, round-robin dispatch) owns M-tiles
// 8c..8c+7 x all 8 N-tiles -> stationary per-XCD set = 2MB A-band + 2MB B = L2.
// Cuts gemm L3 re-fetch ~256MB -> ~48MB. global_load_lds both operands.
__global__ __launch_bounds__(256, 2) void gemm1_kernel(const bf16_t* __restrict__ A,
                                                       const bf16_t* __restrict__ Bt,
                                                       bf16_t* __restrict__ C) {
  constexpr int BM = 128, BN = 128, Kd = FEAT;
  constexpr int LDSA = BM * 64;   // BM rows x 32 k x 2B
  constexpr int LDSB = BN * 64;
  __shared__ char lds[2][LDSA + LDSB];
  const int tid = threadIdx.x;
  const int wid = tid >> 6, lane = tid & 63;
  const int b = blockIdx.x;                      // 512 blocks
  const int xcd = b & 7, j = b >> 3;             // j in 0..63
  const int bm0 = (xcd * 8 + (j >> 3)) * BM;     // M-tile 0..63 (8 per XCD)
  const int bn0 = (j & 7) * BN;                  // N-tile 0..7
  const int wr = wid >> 1, wc = wid & 1;
  constexpr int WM = BM / 2, WN = BN / 2;
  constexpr int NMI = WM / 16, NNI = WN / 16;

  auto stage = [&](int buf, int t) {
    const int k0 = t * 32;
#pragma unroll
    for (int li = 0; li < BM / 64; ++li) {
      const int rb = wid * (BM / 4) + li * 16;
      const int r = rb + (lane >> 2);
      const int sdat = (lane & 3) ^ (r & 3);
      const bf16_t* g = A + (size_t)(bm0 + r) * Kd + k0 + sdat * 8;
      __builtin_amdgcn_global_load_lds((gvoid_t*)g, (lvoid_t*)&lds[buf][rb * 64], 16, 0, 0);
    }
#pragma unroll
    for (int li = 0; li < BN / 64; ++li) {
      const int rb = wid * (BN / 4) + li * 16;
      const int r = rb + (lane >> 2);
      const int sdat = (lane & 3) ^ (r & 3);
      const bf16_t* g = Bt + (size_t)(bn0 + r) * Kd + k0 + sdat * 8;
      __builtin_amdgcn_global_load_lds((gvoid_t*)g, (lvoid_t*)&lds[buf][LDSA + rb * 64], 16, 0, 0);
    }
  };

  f32x4 acc[NMI][NNI];
#pragma unroll
  for (int mi = 0; mi < NMI; ++mi)
#pragma unroll
    for (int ni = 0; ni < NNI; ++ni) acc[mi][ni] = (f32x4){0.f, 0.f, 0.f, 0.f};

  const int nT = Kd / 32;
  stage(0, 0);
  __syncthreads();
  for (int t = 0; t < nT; ++t) {
    const int cur = t & 1;
    if (t + 1 < nT) stage(cur ^ 1, t + 1);
    const char* la = &lds[cur][0];
    const char* lb = &lds[cur][LDSA];
    const int s = lane >> 4;
    bf16x8 af[NMI], bfr[NNI];
#pragma unroll
    for (int mi = 0; mi < NMI; ++mi) {
      const int m = wr * WM + mi * 16 + (lane & 15);
      af[mi] = *(const bf16x8*)(la + m * 64 + ((s ^ (m & 3)) * 16));
    }
#pragma unroll
    for (int ni = 0; ni < NNI; ++ni) {
      const int n = wc * WN + ni * 16 + (lane & 15);
      bfr[ni] = *(const bf16x8*)(lb + n * 64 + ((s ^ (n & 3)) * 16));
    }
#pragma unroll
    for (int mi = 0; mi < NMI; ++mi)
#pragma unroll
      for (int ni = 0; ni < NNI; ++ni)
        acc[mi][ni] = __builtin_amdgcn_mfma_f32_16x16x32_bf16(af[mi], bfr[ni], acc[mi][ni], 0, 0, 0);
    __syncthreads();
  }

#pragma unroll
  for (int mi = 0; mi < NMI; ++mi)
#pragma unroll
    for (int ni = 0; ni < NNI; ++ni)
#pragma unroll
      for (int j4 = 0; j4 < 4; ++j4) {
        const int r = bm0 + wr * WM + mi * 16 + (lane >> 4) * 4 + j4;
        const int c = bn0 + wc * WN + ni * 16 + (lane & 15);
        C[(size_t)r * FEAT + c] = (__bf16)acc[mi][ni][j4];
      }
}

// ------- fused spmm1+bias+relu+gemm2, 8-way feature-split for L2 locality -------
// block = (row-group rg, chunk c); c = blockIdx&7 -> chunk c pinned to XCD c
// (round-robin dispatch) -> each XCD's stationary gather set = 2MB slice of xW1.
// K-partials stored as bf16 (halves part traffic; adds <=4e-3 logit error).
#define SROWS  16
#define SCHUNK 128
#define NCHUNK 8
__global__ __launch_bounds__(256) void spmm_gemm2_kernel(const bf16_t* __restrict__ xW1,
                                                         const int* __restrict__ idxm,
                                                         const float* __restrict__ wm,
                                                         const float* __restrict__ b1,
                                                         const bf16_t* __restrict__ W2t,
                                                         bf16_t* __restrict__ part) {
  const int tid = threadIdx.x;
  const int c  = blockIdx.x & (NCHUNK - 1);
  const int rg = blockIdx.x >> 3;
  const int r0 = rg * SROWS;
  const int f0 = c * SCHUNK;
  __shared__ int    snb[SROWS][TK];
  __shared__ float  swt[SROWS][TK];
  __shared__ bf16_t hls[SROWS][SCHUNK];  // XOR-swizzled groups of 8
  ((int2*)&snb[0][0])[tid]   = ((const int2*)(idxm + (size_t)r0 * TK))[tid];
  ((float2*)&swt[0][0])[tid] = ((const float2*)(wm + (size_t)r0 * TK))[tid];
  __syncthreads();
  const int wid = tid >> 6, lane = tid & 63;
  const int gr = tid >> 4;            // gather row 0..15
  const int gc = (tid & 15) * 8;      // feat base within chunk (8 feats/thread)

  float a[8];
#pragma unroll
  for (int j = 0; j < 8; ++j) a[j] = 0.f;
#pragma unroll 8
  for (int k = 0; k < TK; ++k) {
    const bf16x8 v = *(const bf16x8*)(xW1 + (size_t)snb[gr][k] * FEAT + f0 + gc);
    const float wk = swt[gr][k];
#pragma unroll
    for (int j = 0; j < 8; ++j) a[j] += wk * (float)v[j];
  }
  const float4 b0 = ((const float4*)(b1 + f0 + gc))[0];
  const float4 b1v = ((const float4*)(b1 + f0 + gc))[1];
  bf16x8 o0;
  o0[0] = (__bf16)fmaxf(a[0] + b0.x, 0.f);
  o0[1] = (__bf16)fmaxf(a[1] + b0.y, 0.f);
  o0[2] = (__bf16)fmaxf(a[2] + b0.z, 0.f);
  o0[3] = (__bf16)fmaxf(a[3] + b0.w, 0.f);
  o0[4] = (__bf16)fmaxf(a[4] + b1v.x, 0.f);
  o0[5] = (__bf16)fmaxf(a[5] + b1v.y, 0.f);
  o0[6] = (__bf16)fmaxf(a[6] + b1v.z, 0.f);
  o0[7] = (__bf16)fmaxf(a[7] + b1v.w, 0.f);
  const int g0 = (gc >> 3);           // group 0..15
  char* hb = (char*)&hls[0][0];
  *(bf16x8*)(hb + gr * (SCHUNK * 2) + ((g0 ^ (gr & 7)) * 16)) = o0;

  // prefetch W2t B-frags before the barrier (independent of LDS writes)
  const int s = lane >> 4;
  const int m = lane & 15;
  const int n = wid * 16 + (lane & 15);
  bf16x8 bfr[SCHUNK / 32];
#pragma unroll
  for (int ks = 0; ks < SCHUNK / 32; ++ks)
    bfr[ks] = *(const bf16x8*)(W2t + (size_t)n * FEAT + f0 + ks * 32 + s * 8);
  __syncthreads();

  // MFMA: out[16 x 64] K-partial (K=SCHUNK); this wave owns cols wid*16..
  f32x4 acc = (f32x4){0.f, 0.f, 0.f, 0.f};
  const char* hr = (char*)&hls[0][0] + m * (SCHUNK * 2);
#pragma unroll
  for (int ks = 0; ks < SCHUNK / 32; ++ks) {
    const int g = ks * 4 + s;
    const bf16x8 afrag = *(const bf16x8*)(hr + ((g ^ (m & 7)) * 16));
    acc = __builtin_amdgcn_mfma_f32_16x16x32_bf16(afrag, bfr[ks], acc, 0, 0, 0);
  }
#pragma unroll
  for (int j = 0; j < 4; ++j) {
    const int r = r0 + (lane >> 4) * 4 + j;
    const int col = wid * 16 + (lane & 15);
    part[((size_t)c * N_NODES + r) * NCLS + col] = (__bf16)acc[j];
  }
}

// ------- out2 = sum of 8 bf16 partials (fixed order, deterministic) -------
__global__ __launch_bounds__(256) void reduce8_kernel(const bf16_t* __restrict__ part,
                                                      float* __restrict__ out2) {
  const int i = blockIdx.x * 256 + threadIdx.x;   // over N*NCLS/8 bf16x8
  float s[8];
  {
    const bf16x8 p = ((const bf16x8*)part)[i];
#pragma unroll
    for (int j = 0; j < 8; ++j) s[j] = (float)p[j];
  }
#pragma unroll
  for (int c = 1; c < NCHUNK; ++c) {
    const bf16x8 p = ((const bf16x8*)(part + (size_t)c * N_NODES * NCLS))[i];
#pragma unroll
    for (int j = 0; j < 8; ++j) s[j] += (float)p[j];
  }
  float4 lo, hi;
  lo.x = s[0]; lo.y = s[1]; lo.z = s[2]; lo.w = s[3];
  hi.x = s[4]; hi.y = s[5]; hi.z = s[6]; hi.w = s[7];
  ((float4*)out2)[i * 2]     = lo;
  ((float4*)out2)[i * 2 + 1] = hi;
}

// ---------------- spmm2 + b2 + log_softmax: one wave per output row ----------------
__global__ __launch_bounds__(256) void final_kernel(const float* __restrict__ out2,
                                                    const int* __restrict__ idxm,
                                                    const float* __restrict__ wm,
                                                    const float* __restrict__ b2,
                                                    float* __restrict__ out) {
  const int wid = threadIdx.x >> 6, lane = threadIdx.x & 63;
  const int row = blockIdx.x * 4 + wid;
  const int kk = lane & 31;
  const float wv = wm[(size_t)row * TK + kk];
  const int   iv = idxm[(size_t)row * TK + kk];
  float acc = 0.f;
#pragma unroll 8
  for (int k = 0; k < TK; ++k) {
    const float wk = __shfl(wv, k);
    const int   ik = __shfl(iv, k);
    acc += wk * out2[(size_t)ik * NCLS + lane];
  }
  const float logit = acc + b2[lane];
  float m = logit;
#pragma unroll
  for (int off = 1; off < 64; off <<= 1) m = fmaxf(m, __shfl_xor(m, off));
  const float e = expf(logit - m);
  float ssum = e;
#pragma unroll
  for (int off = 1; off < 64; off <<= 1) ssum += __shfl_xor(ssum, off);
  out[(size_t)row * NCLS + lane] = (logit - m) - logf(ssum);
}

extern "C" void kernel_launch(void* const* d_in, const int* in_sizes, int n_in,
                              void* d_out, int out_size, void* d_ws, size_t ws_size,
                              hipStream_t stream) {
  (void)in_sizes; (void)n_in; (void)out_size; (void)ws_size;
  const float* x     = (const float*)d_in[0];
  const float* adj   = (const float*)d_in[1];
  const float* W1    = (const float*)d_in[2];
  const float* b1    = (const float*)d_in[3];
  const float* W2    = (const float*)d_in[4];
  const float* b2    = (const float*)d_in[5];
  const float* alpha = (const float*)d_in[6];

  char* ws = (char*)d_ws;
  const size_t MB = 1024 * 1024;
  bf16_t* x_bf = (bf16_t*)(ws + 0 * MB);    // 16 MB
  bf16_t* xW1  = (bf16_t*)(ws + 16 * MB);   // 16 MB
  bf16_t* W1t  = (bf16_t*)(ws + 48 * MB);   // 2 MB
  bf16_t* W2t  = (bf16_t*)(ws + 50 * MB);   // 128KB
  float*  out2 = (float*)(ws + 51 * MB);    // 2 MB
  int*    idxm = (int*)(ws + 53 * MB);      // 1 MB
  float*  wm   = (float*)(ws + 54 * MB);    // 1 MB
  bf16_t* part = (bf16_t*)(ws + 56 * MB);   // 8 MB: 8 x [8192][64] bf16 K-partials

  topk_kernel<<<dim3(N_NODES + 272), dim3(256), 0, stream>>>(
      adj, alpha, x, x_bf, idxm, wm, W1, W1t, W2, W2t);
  gemm1_kernel<<<dim3(512), dim3(256), 0, stream>>>(x_bf, W1t, xW1);
  spmm_gemm2_kernel<<<dim3((N_NODES / SROWS) * NCHUNK), dim3(256), 0, stream>>>(
      xW1, idxm, wm, b1, W2t, part);
  reduce8_kernel<<<dim3(N_NODES * NCLS / 8 / 256), dim3(256), 0, stream>>>(part, out2);
  final_kernel<<<dim3(N_NODES / 4), dim3(256), 0, stream>>>(out2, idxm, wm, b2, (float*)d_out);
}